// Round 7
// baseline (130.256 us; speedup 1.0000x reference)
//
#include <hip/hip_runtime.h>

typedef __attribute__((ext_vector_type(4)))  int   int4v;
typedef __attribute__((ext_vector_type(16))) int   int16v;
typedef __attribute__((ext_vector_type(4)))  float float4v;

// XOR swizzle of the 16B slot within a 64B K-row (round-0 proven layout).
__device__ __forceinline__ int swz(int row, int slot) {
    return slot ^ ((row ^ (row >> 2)) & 3);
}

// Fake-quant grid index, bit-exact vs reference (round-3 validated):
// reciprocal fast path + rare exact-division tie fixup.
__device__ __forceinline__ int4v quant4(float4v v, float lo, float up,
                                        float scale, float inv) {
    float t0 = fminf(fmaxf(v[0], lo), up) - lo;
    float t1 = fminf(fmaxf(v[1], lo), up) - lo;
    float t2 = fminf(fmaxf(v[2], lo), up) - lo;
    float t3 = fminf(fmaxf(v[3], lo), up) - lo;
    float m0 = t0 * inv, m1 = t1 * inv, m2 = t2 * inv, m3 = t3 * inv;
    float r0 = rintf(m0), r1 = rintf(m1), r2 = rintf(m2), r3 = rintf(m3);
    float d0 = fabsf(fabsf(m0 - r0) - 0.5f);
    float d1 = fabsf(fabsf(m1 - r1) - 0.5f);
    float d2 = fabsf(fabsf(m2 - r2) - 0.5f);
    float d3 = fabsf(fabsf(m3 - r3) - 0.5f);
    if (fminf(fminf(d0, d1), fminf(d2, d3)) < 1e-4f) {   // rare tie-suspect
        r0 = rintf(t0 / scale); r1 = rintf(t1 / scale);
        r2 = rintf(t2 / scale); r3 = rintf(t3 / scale);
    }
    int4v q = {(int)r0, (int)r1, (int)r2, (int)r3};
    return q;
}

__device__ __forceinline__ unsigned bsum(int p) {        // sum of 4 bytes (<=15 each)
    return ((unsigned)p * 0x01010101u) >> 24;
}

// Grid = 2 blocks per batch: block handles 128 A-rows x all 256 B-cols.
// batch = bid >> 1, half = bid & 1  (pair temporally adjacent -> B hits L2/L3
// on the second quantization pass).
__global__ __launch_bounds__(256, 6) void qmm_kernel(
    const float* __restrict__ A, const float* __restrict__ B,
    const float* __restrict__ aLo, const float* __restrict__ aUp,
    const float* __restrict__ bLo, const float* __restrict__ bUp,
    float* __restrict__ Out)
{
    // qA: [row 0..127][k 0..63] i8 (16B slot = 16 consecutive k), slot-swizzled
    // qB: B^T -> [col 0..255][k 0..63] i8, same layout
    __shared__ int   qA[128 * 16];
    __shared__ int   qB[256 * 16];
    __shared__ float RAf[128];   // sA*lB*rowsum(qA[i]) + 32*lA*lB
    __shared__ float CBf[256];   // lA*sB*colsum(qB[j]) + 32*lA*lB

    const int tid  = threadIdx.x;
    const int bid  = blockIdx.x;
    const int b    = bid >> 1;
    const int half = bid & 1;

    const float lA = aLo[0], uA = aUp[0];
    const float lB = bLo[0], uB = bUp[0];
    const float sA  = (uA - lA) / 15.0f;
    const float sB  = (uB - lB) / 15.0f;
    const float iA  = 1.0f / sA;
    const float iB  = 1.0f / sB;
    const float sAB = sA * sB;

    const float4v* A4 = (const float4v*)(A + (size_t)b * 256 * 64 + (size_t)half * 128 * 64);
    const float4v* B4 = (const float4v*)(B + (size_t)b * 64 * 256);
    float* outb = Out + (size_t)b * 256 * 256 + (size_t)half * 128 * 256;

    // ---- stage A: 128 rows, dense coalesced float4 loads, pack 4 x i8 -> int
    #pragma unroll
    for (int it = 0; it < 8; ++it) {
        int f = it * 256 + tid;            // float4 index 0..2047
        float4v v = A4[f];
        int4v q = quant4(v, lA, uA, sA, iA);
        int p  = q[0] | (q[1] << 8) | (q[2] << 16) | (q[3] << 24);
        int row = f >> 4, chunk = f & 15;  // row 0..127, 16 ints per row
        qA[row * 16 + swz(row, chunk >> 2) * 4 + (chunk & 3)] = p;
    }

    // ---- stage B: coalesced loads of 4x4 fp32 tile, transpose in regs ----
    const int u  = tid & 63;   // column group: cols 4u..4u+3
    const int kg = tid >> 6;   // wave id -> 4-byte offset inside 16B k-slot
    #pragma unroll
    for (int kb = 0; kb < 4; ++kb) {
        int k0 = kb * 16 + kg * 4;         // k rows k0..k0+3
        int4v q0 = quant4(B4[(size_t)(k0 + 0) * 64 + u], lB, uB, sB, iB);
        int4v q1 = quant4(B4[(size_t)(k0 + 1) * 64 + u], lB, uB, sB, iB);
        int4v q2 = quant4(B4[(size_t)(k0 + 2) * 64 + u], lB, uB, sB, iB);
        int4v q3 = quant4(B4[(size_t)(k0 + 3) * 64 + u], lB, uB, sB, iB);
        #pragma unroll
        for (int c = 0; c < 4; ++c) {
            int col = u * 4 + c;
            int p = q0[c] | (q1[c] << 8) | (q2[c] << 16) | (q3[c] << 24);
            qB[col * 16 + swz(col, kb) * 4 + kg] = p;
        }
    }

    __syncthreads();

    // ---- col sums (all threads) and row sums (tid < 128), byte-sum trick ----
    {
        unsigned sb = 0;
        #pragma unroll
        for (int j = 0; j < 16; ++j)
            sb += bsum((unsigned)qB[tid * 16 + swz(tid, j >> 2) * 4 + (j & 3)]);
        float c32 = 32.0f * lA * lB;
        CBf[tid] = lA * sB * (float)sb + c32;
        if (tid < 128) {
            unsigned sa = 0;
            #pragma unroll
            for (int j = 0; j < 16; ++j)
                sa += bsum((unsigned)qA[tid * 16 + swz(tid, j >> 2) * 4 + (j & 3)]);
            RAf[tid] = sA * lB * (float)sa + c32;
        }
    }
    __syncthreads();

    // ---- compute: 32x32x32 i8 MFMA; wave w owns rows 32w..32w+31, all 8 col-tiles
    // A/B operand: lane&31 = row/col, lane>>5 = k-half, 16B contiguous k.
    // C/D: col = lane&31, row = (reg&3) + 8*(reg>>2) + 4*(lane>>5).
    const int lane = tid & 63, wave = tid >> 6;
    const int ln = lane & 31, h = lane >> 5;

    const int4v* qA4 = (const int4v*)qA;
    const int4v* qB4 = (const int4v*)qB;
    const int16v z16 = {0,0,0,0,0,0,0,0,0,0,0,0,0,0,0,0};

    const int rbase = wave * 32;
    const int arow  = rbase + ln;
    int4v af0 = qA4[arow * 4 + swz(arow, 0 + h)];   // kstep 0
    int4v af1 = qA4[arow * 4 + swz(arow, 2 + h)];   // kstep 1

    float4v RA[4];
    #pragma unroll
    for (int g = 0; g < 4; ++g)
        RA[g] = *(const float4v*)&RAf[rbase + 8 * g + 4 * h];

    #pragma unroll 2
    for (int ct = 0; ct < 8; ++ct) {
        const int col = ct * 32 + ln;
        int4v bf0 = qB4[col * 4 + swz(col, 0 + h)];
        int4v bf1 = qB4[col * 4 + swz(col, 2 + h)];
        float cb  = CBf[col];

        int16v acc = __builtin_amdgcn_mfma_i32_32x32x32_i8(af0, bf0, z16, 0, 0, 0);
        acc        = __builtin_amdgcn_mfma_i32_32x32x32_i8(af1, bf1, acc, 0, 0, 0);

        #pragma unroll
        for (int g = 0; g < 4; ++g) {
            const int row0 = rbase + 8 * g + 4 * h;
            #pragma unroll
            for (int j = 0; j < 4; ++j) {
                // lanes 0-31 and 32-63 each cover one full 128B line
                outb[(size_t)(row0 + j) * 256 + col] =
                    fmaf(sAB, (float)acc[g * 4 + j], RA[g][j] + cb);
            }
        }
    }
}

extern "C" void kernel_launch(void* const* d_in, const int* in_sizes, int n_in,
                              void* d_out, int out_size, void* d_ws, size_t ws_size,
                              hipStream_t stream) {
    const float* A   = (const float*)d_in[0];
    const float* B   = (const float*)d_in[1];
    const float* aLo = (const float*)d_in[2];
    const float* aUp = (const float*)d_in[3];
    const float* bLo = (const float*)d_in[4];
    const float* bUp = (const float*)d_in[5];
    float* Out = (float*)d_out;

    int batches = in_sizes[0] / (256 * 64);   // 128*8 = 1024
    qmm_kernel<<<batches * 2, 256, 0, stream>>>(A, B, aLo, aUp, bLo, bUp, Out);
}